// Round 14
// baseline (76.314 us; speedup 1.0000x reference)
//
#include <hip/hip_runtime.h>
#include <math.h>

// FFT circular conv: y[b,h,:] = irfft(rfft(x[b,h,:]) * rfft(k[h,:])), N=4096.
// TWO-ROW SCHEME (z = x[r0] + i*x[r1], k real => one pointwise serves both)
// + PERSISTENT MULTI-PAIR BLOCKS: each block processes NPB=6 pairs; the next
// pair's global loads are issued ~8us early (register prefetch, double-
// buffered reg sets with static indexing); stores drain under next compute.
// Grid 512 blocks = exactly 2 resident/CU (64KB LDS) -> no dispatch tail.
// 4096 = 8^4 radix-8 Stockham, ping-pong LDS (1 barrier/stage), kf multiply
// fused into fwd final stage (mirror-conj half-spectrum), re/im [64|64]
// grouped words + SW v2 swizzle, serial sincos chains, v_sin/v_cos in revs.

#define NT 512
#define NPB 6
#define KF_LD 2049
#define C_SQRT1_2 0.70710678118654752f
#define INV_4096 2.44140625e-4f

// Word swizzle (bijective involution, keyed on bits>=5).
#define SW(a) ((a) ^ (((a) >> 5) & 31) ^ (((a) >> 2) & 24))
// Point index -> LDS word index of re part (im at +64).
__device__ __forceinline__ int WP(int a) {
  const int s = SW(a);
  return 2 * s - (s & 63);
}

// sn = sin(2*pi*f), cs = cos(2*pi*f); f pre-reduced to [0,1).
__device__ __forceinline__ void sincos_rev(float f, float& sn, float& cs) {
  float s_, c_;
  asm("v_sin_f32 %0, %1" : "=v"(s_) : "v"(f));
  asm("v_cos_f32 %0, %1" : "=v"(c_) : "v"(f));
  sn = s_; cs = c_;
}

template <int SIGN>
__device__ __forceinline__ void bf8(const float ar[8], const float ai[8],
                                    float br[8], float bi[8]) {
  float s0r = ar[0] + ar[4], s0i = ai[0] + ai[4];
  float s1r = ar[0] - ar[4], s1i = ai[0] - ai[4];
  float s2r = ar[2] + ar[6], s2i = ai[2] + ai[6];
  float s3r = ar[2] - ar[6], s3i = ai[2] - ai[6];
  float E0r = s0r + s2r, E0i = s0i + s2i;
  float E2r = s0r - s2r, E2i = s0i - s2i;
  float E1r, E1i, E3r, E3i;
  if (SIGN < 0) { E1r = s1r + s3i; E1i = s1i - s3r; E3r = s1r - s3i; E3i = s1i + s3r; }
  else          { E1r = s1r - s3i; E1i = s1i + s3r; E3r = s1r + s3i; E3i = s1i - s3r; }
  float u0r = ar[1] + ar[5], u0i = ai[1] + ai[5];
  float u1r = ar[1] - ar[5], u1i = ai[1] - ai[5];
  float u2r = ar[3] + ar[7], u2i = ai[3] + ai[7];
  float u3r = ar[3] - ar[7], u3i = ai[3] - ai[7];
  float O0r = u0r + u2r, O0i = u0i + u2i;
  float O2r = u0r - u2r, O2i = u0i - u2i;
  float O1r, O1i, O3r, O3i;
  if (SIGN < 0) { O1r = u1r + u3i; O1i = u1i - u3r; O3r = u1r - u3i; O3i = u1i + u3r; }
  else          { O1r = u1r - u3i; O1i = u1i + u3r; O3r = u1r + u3i; O3i = u1i - u3r; }
  float t1r, t1i, t2r, t2i, t3r, t3i;
  if (SIGN < 0) {
    t1r = C_SQRT1_2 * (O1r + O1i); t1i = C_SQRT1_2 * (O1i - O1r);
    t2r = O2i;  t2i = -O2r;
    t3r = C_SQRT1_2 * (O3i - O3r); t3i = -C_SQRT1_2 * (O3r + O3i);
  } else {
    t1r = C_SQRT1_2 * (O1r - O1i); t1i = C_SQRT1_2 * (O1i + O1r);
    t2r = -O2i; t2i = O2r;
    t3r = -C_SQRT1_2 * (O3r + O3i); t3i = C_SQRT1_2 * (O3r - O3i);
  }
  br[0] = E0r + O0r; bi[0] = E0i + O0i;
  br[4] = E0r - O0r; bi[4] = E0i - O0i;
  br[1] = E1r + t1r; bi[1] = E1i + t1i;
  br[5] = E1r - t1r; bi[5] = E1i - t1i;
  br[2] = E2r + t2r; bi[2] = E2i + t2i;
  br[6] = E2r - t2r; bi[6] = E2i - t2i;
  br[3] = E3r + t3r; bi[3] = E3i + t3i;
  br[7] = E3r - t3r; bi[7] = E3i - t3i;
}

// Twiddled scatter-write: Y[ob+S*m] = b[m] * w^m, w = e^{SIGN*2*pi*i*f1}.
template <int SIGN, int S>
__device__ __forceinline__ void tw_write(float* Y, int ob,
                                         const float br[8], const float bi[8],
                                         float f1) {
  { const int i0 = WP(ob); Y[i0] = br[0]; Y[i0 + 64] = bi[0]; }
  float sn, cs;
  sincos_rev(f1, sn, cs);
  const float w1r = cs, w1i = (SIGN > 0) ? sn : -sn;
  float cwr = w1r, cwi = w1i;
#pragma unroll
  for (int m = 1; m < 8; ++m) {
    const int idx = WP(ob + S * m);
    Y[idx] = br[m] * cwr - bi[m] * cwi;
    Y[idx + 64] = br[m] * cwi + bi[m] * cwr;
    if (m < 7) {
      const float nr = cwr * w1r - cwi * w1i;
      const float ni = cwr * w1i + cwi * w1r;
      cwr = nr; cwi = ni;
    }
  }
}

// Out-of-place interior Stockham radix-8 stage. No internal barrier.
template <int SIGN, int S>
__device__ __forceinline__ void stage_r8(const float* X, float* Y,
                                         const int rd[8]) {
  const int t = (int)threadIdx.x;
  const int q = t & (S - 1);
  const int p = t / S;
  float ar[8], ai[8];
#pragma unroll
  for (int j = 0; j < 8; ++j) {
    ar[j] = X[rd[j]];
    ai[j] = X[rd[j] + 64];
  }
  float br[8], bi[8];
  bf8<SIGN>(ar, ai, br, bi);
  tw_write<SIGN, S>(Y, q + 8 * S * p, br, bi, (float)(S * p) * INV_4096);
}

// Conv fwd final stage (S=512, p=0, twiddle-free) + pointwise kf multiply.
// Kfull[k] = k<=2048 ? kf[k] : conj(kf[4096-k]).
__device__ __forceinline__ void stage4_kf(const float* X, float* Y,
                                          const float2* __restrict__ kfrow,
                                          const int rd[8]) {
  const int t = (int)threadIdx.x;
  float ar[8], ai[8];
#pragma unroll
  for (int j = 0; j < 8; ++j) {
    ar[j] = X[rd[j]];
    ai[j] = X[rd[j] + 64];
  }
  float br[8], bi[8];
  bf8<-1>(ar, ai, br, bi);
#pragma unroll
  for (int m = 0; m < 8; ++m) {
    const int k = t + 512 * m;
    float2 kv;
    if (m <= 3) {
      kv = kfrow[k];                    // k <= 2047
    } else {
      kv = kfrow[4096 - k];             // t==0,m==4 -> 2048 (Nyquist)
      kv.y = -kv.y;
    }
    const int i = rd[m];
    Y[i] = br[m] * kv.x - bi[m] * kv.y;
    Y[i + 64] = br[m] * kv.y + bi[m] * kv.x;
  }
}

// Inverse final stage (S=512, twiddle-free), store re->row0, im->row1.
__device__ __forceinline__ void stage4_store(const float* X,
                                             float* __restrict__ y0,
                                             float* __restrict__ y1,
                                             const int rd[8]) {
  const int t = (int)threadIdx.x;
  float ar[8], ai[8];
#pragma unroll
  for (int j = 0; j < 8; ++j) {
    ar[j] = X[rd[j]];
    ai[j] = X[rd[j] + 64];
  }
  float br[8], bi[8];
  bf8<1>(ar, ai, br, bi);
#pragma unroll
  for (int m = 0; m < 8; ++m) {
    const int k = t + 512 * m;
    y0[k] = br[m];
    y1[k] = bi[m];
  }
}

// One full pair: stage1 from preloaded regs (arC/aiC), then prefetch the
// next pair's rows into arN/aiN (hidden under the remaining 7 stages).
__device__ __forceinline__ void conv_pair(const float* __restrict__ x,
                                          float* __restrict__ y,
                                          const float2* __restrict__ kf,
                                          int H, int p, int pmax,
                                          float (&arC)[8], float (&aiC)[8],
                                          float (&arN)[8], float (&aiN)[8],
                                          float* A_, float* B_,
                                          const int rd[8]) {
  const int t = (int)threadIdx.x;
  const int h = p % H, b2 = p / H;
  const size_t r0 = ((size_t)(2 * b2) * H + (size_t)h) * 4096;
  float* d0 = y + r0;
  float* d1 = d0 + (size_t)H * 4096;
  const float2* kfrow = kf + (size_t)h * KF_LD;
  {  // fwd S=1 from registers
    float br[8], bi[8];
    bf8<-1>(arC, aiC, br, bi);
    tw_write<-1, 1>(A_, 8 * t, br, bi, (float)t * INV_4096);
  }
  __syncthreads();
  {  // issue next pair's loads (clamped; results needed only next call)
    const int pn = (p + 1 < pmax) ? p + 1 : p;
    const int hn = pn % H, bn = pn / H;
    const float* s0 = x + ((size_t)(2 * bn) * H + (size_t)hn) * 4096;
    const float* s1 = s0 + (size_t)H * 4096;
#pragma unroll
    for (int j = 0; j < 8; ++j) {
      arN[j] = s0[t + 512 * j];
      aiN[j] = s1[t + 512 * j];
    }
  }
  stage_r8<-1, 8>(A_, B_, rd);   __syncthreads();
  stage_r8<-1, 64>(B_, A_, rd);  __syncthreads();
  stage4_kf(A_, B_, kfrow, rd);  __syncthreads();
  stage_r8<1, 1>(B_, A_, rd);    __syncthreads();
  stage_r8<1, 8>(A_, B_, rd);    __syncthreads();
  stage_r8<1, 64>(B_, A_, rd);   __syncthreads();
  stage4_store(A_, d0, d1, rd);
  __syncthreads();               // protect A_/B_ before next pair's stage1
}

// kfft: real input, in-place compact version (tiny kernel, 768 blocks).
__device__ __forceinline__ void stage_r8_ip_k(float* Z, const int rd[8],
                                              int S_, int dummy);
template <int S>
__device__ __forceinline__ void stage_r8_ip(float* Z, const int rd[8]) {
  const int t = (int)threadIdx.x;
  const int q = t & (S - 1);
  const int p = t / S;
  float ar[8], ai[8];
#pragma unroll
  for (int j = 0; j < 8; ++j) {
    ar[j] = Z[rd[j]];
    ai[j] = Z[rd[j] + 64];
  }
  __syncthreads();
  float br[8], bi[8];
  bf8<-1>(ar, ai, br, bi);
  tw_write<-1, S>(Z, q + 8 * S * p, br, bi, (float)(S * p) * INV_4096);
  __syncthreads();
}

__global__ __launch_bounds__(NT) void kfft_kernel(const float* __restrict__ kin,
                                                  float2* __restrict__ kf) {
  __shared__ float Z_[8192];
  const int t = (int)threadIdx.x;
  const int h = (int)blockIdx.x;
  int rd[8];
#pragma unroll
  for (int j = 0; j < 8; ++j) rd[j] = WP(t + 512 * j);
  {  // stage 1: real input
    const float* src = kin + (size_t)h * 4096;
    float ar[8], ai[8];
#pragma unroll
    for (int j = 0; j < 8; ++j) { ar[j] = src[t + 512 * j]; ai[j] = 0.0f; }
    float br[8], bi[8];
    bf8<-1>(ar, ai, br, bi);
    tw_write<-1, 1>(Z_, 8 * t, br, bi, (float)t * INV_4096);
  }
  __syncthreads();
  stage_r8_ip<8>(Z_, rd);
  stage_r8_ip<64>(Z_, rd);
  {  // final stage + half-spectrum store, 1/4096 scale folded
    float ar[8], ai[8];
#pragma unroll
    for (int j = 0; j < 8; ++j) { ar[j] = Z_[rd[j]]; ai[j] = Z_[rd[j] + 64]; }
    float br[8], bi[8];
    bf8<-1>(ar, ai, br, bi);
    const float sc = 1.0f / 4096.0f;
    float2* kfrow = kf + (size_t)h * KF_LD;
#pragma unroll
    for (int m = 0; m < 4; ++m) {
      const int k = t + 512 * m;  // 0..2047
      kfrow[k] = make_float2(br[m] * sc, bi[m] * sc);
    }
    if (t == 0) kfrow[2048] = make_float2(br[4] * sc, bi[4] * sc);
  }
}

__global__ __launch_bounds__(NT) void conv_kernel(const float* __restrict__ x,
                                                  const float2* __restrict__ kf,
                                                  float* __restrict__ y, int H,
                                                  int pmax) {
  __shared__ float A_[8192];
  __shared__ float B_[8192];
  const int t = (int)threadIdx.x;
  int rd[8];
#pragma unroll
  for (int j = 0; j < 8; ++j) rd[j] = WP(t + 512 * j);
  const int p0 = (int)blockIdx.x * NPB;
  float arA[8], aiA[8], arB[8], aiB[8];
  {  // prologue: load pair p0 into buffer A
    const int h = p0 % H, b2 = p0 / H;
    const float* s0 = x + ((size_t)(2 * b2) * H + (size_t)h) * 4096;
    const float* s1 = s0 + (size_t)H * 4096;
#pragma unroll
    for (int j = 0; j < 8; ++j) {
      arA[j] = s0[t + 512 * j];
      aiA[j] = s1[t + 512 * j];
    }
  }
  for (int ii = 0; ii < NPB; ii += 2) {  // 2x unroll: static reg-buffer parity
    conv_pair(x, y, kf, H, p0 + ii, pmax, arA, aiA, arB, aiB, A_, B_, rd);
    conv_pair(x, y, kf, H, p0 + ii + 1, pmax, arB, aiB, arA, aiA, A_, B_, rd);
  }
}

extern "C" void kernel_launch(void* const* d_in, const int* in_sizes, int n_in,
                              void* d_out, int out_size, void* d_ws, size_t ws_size,
                              hipStream_t stream) {
  const float* x = (const float*)d_in[0];
  const float* kin = (const float*)d_in[1];
  float* y = (float*)d_out;
  const int H = in_sizes[1] / 4096;    // 768
  const int BH = in_sizes[0] / 4096;   // 6144 rows -> 3072 pairs
  const int pairs = BH / 2;
  const int blocks = pairs / NPB;      // 512 = exactly 2 resident blocks/CU
  float2* kf = (float2*)d_ws;          // 768*2049*8B = 12.59 MB
  hipLaunchKernelGGL(kfft_kernel, dim3(H), dim3(NT), 0, stream, kin, kf);
  hipLaunchKernelGGL(conv_kernel, dim3(blocks), dim3(NT), 0, stream, x, kf, y, H,
                     pairs);
}

// Round 15
// 60.583 us; speedup vs baseline: 1.2597x; 1.2597x over previous
//
#include <hip/hip_runtime.h>
#include <math.h>

// FFT circular conv: y[b,h,:] = irfft(rfft(x[b,h,:]) * rfft(k[h,:])), N=4096.
// TWO-ROW SCHEME (z = x[r0] + i*x[r1]; k real => one pointwise serves both).
// Round 15: MID-FUSION — fwd final stage (S=512) outputs spectrum points
// k = t+512m in-thread; inverse S=1 stage consumes exactly the same set.
// So fwd-final -> Kfull multiply -> inv-S=1 run entirely in registers:
// one full LDS round-trip (+2 barriers) removed. 6 LDS traversals total.
// 4096 = 8^4 radix-8 Stockham, ping-pong LDS, re/im [64|64] grouped words
// (ds_read2/write2), SW v2 swizzle (<=2-way), serial sincos twiddle chains,
// v_sin/v_cos in revolutions. 512-thread blocks, 64 KB LDS.

#define NT 512
#define KF_LD 2049
#define C_SQRT1_2 0.70710678118654752f
#define INV_4096 2.44140625e-4f

// Word swizzle (bijective involution, keyed on bits>=5).
#define SW(a) ((a) ^ (((a) >> 5) & 31) ^ (((a) >> 2) & 24))
// Point index -> LDS word index of re part (im at +64).
__device__ __forceinline__ int WP(int a) {
  const int s = SW(a);
  return 2 * s - (s & 63);
}

// sn = sin(2*pi*f), cs = cos(2*pi*f); f pre-reduced to [0,1).
__device__ __forceinline__ void sincos_rev(float f, float& sn, float& cs) {
  float s_, c_;
  asm("v_sin_f32 %0, %1" : "=v"(s_) : "v"(f));
  asm("v_cos_f32 %0, %1" : "=v"(c_) : "v"(f));
  sn = s_; cs = c_;
}

template <int SIGN>
__device__ __forceinline__ void bf8(const float ar[8], const float ai[8],
                                    float br[8], float bi[8]) {
  float s0r = ar[0] + ar[4], s0i = ai[0] + ai[4];
  float s1r = ar[0] - ar[4], s1i = ai[0] - ai[4];
  float s2r = ar[2] + ar[6], s2i = ai[2] + ai[6];
  float s3r = ar[2] - ar[6], s3i = ai[2] - ai[6];
  float E0r = s0r + s2r, E0i = s0i + s2i;
  float E2r = s0r - s2r, E2i = s0i - s2i;
  float E1r, E1i, E3r, E3i;
  if (SIGN < 0) { E1r = s1r + s3i; E1i = s1i - s3r; E3r = s1r - s3i; E3i = s1i + s3r; }
  else          { E1r = s1r - s3i; E1i = s1i + s3r; E3r = s1r + s3i; E3i = s1i - s3r; }
  float u0r = ar[1] + ar[5], u0i = ai[1] + ai[5];
  float u1r = ar[1] - ar[5], u1i = ai[1] - ai[5];
  float u2r = ar[3] + ar[7], u2i = ai[3] + ai[7];
  float u3r = ar[3] - ar[7], u3i = ai[3] - ai[7];
  float O0r = u0r + u2r, O0i = u0i + u2i;
  float O2r = u0r - u2r, O2i = u0i - u2i;
  float O1r, O1i, O3r, O3i;
  if (SIGN < 0) { O1r = u1r + u3i; O1i = u1i - u3r; O3r = u1r - u3i; O3i = u1i + u3r; }
  else          { O1r = u1r - u3i; O1i = u1i + u3r; O3r = u1r + u3i; O3i = u1i - u3r; }
  float t1r, t1i, t2r, t2i, t3r, t3i;
  if (SIGN < 0) {
    t1r = C_SQRT1_2 * (O1r + O1i); t1i = C_SQRT1_2 * (O1i - O1r);
    t2r = O2i;  t2i = -O2r;
    t3r = C_SQRT1_2 * (O3i - O3r); t3i = -C_SQRT1_2 * (O3r + O3i);
  } else {
    t1r = C_SQRT1_2 * (O1r - O1i); t1i = C_SQRT1_2 * (O1i + O1r);
    t2r = -O2i; t2i = O2r;
    t3r = -C_SQRT1_2 * (O3r + O3i); t3i = C_SQRT1_2 * (O3r - O3i);
  }
  br[0] = E0r + O0r; bi[0] = E0i + O0i;
  br[4] = E0r - O0r; bi[4] = E0i - O0i;
  br[1] = E1r + t1r; bi[1] = E1i + t1i;
  br[5] = E1r - t1r; bi[5] = E1i - t1i;
  br[2] = E2r + t2r; bi[2] = E2i + t2i;
  br[6] = E2r - t2r; bi[6] = E2i - t2i;
  br[3] = E3r + t3r; bi[3] = E3i + t3i;
  br[7] = E3r - t3r; bi[7] = E3i - t3i;
}

// Twiddled scatter-write: Y[ob+S*m] = b[m] * w^m, w = e^{SIGN*2*pi*i*f1}.
// Serial power chain (one live pair -> minimal VGPR).
template <int SIGN, int S>
__device__ __forceinline__ void tw_write(float* Y, int ob,
                                         const float br[8], const float bi[8],
                                         float f1) {
  { const int i0 = WP(ob); Y[i0] = br[0]; Y[i0 + 64] = bi[0]; }
  float sn, cs;
  sincos_rev(f1, sn, cs);
  const float w1r = cs, w1i = (SIGN > 0) ? sn : -sn;
  float cwr = w1r, cwi = w1i;
#pragma unroll
  for (int m = 1; m < 8; ++m) {
    const int idx = WP(ob + S * m);
    Y[idx] = br[m] * cwr - bi[m] * cwi;
    Y[idx + 64] = br[m] * cwi + bi[m] * cwr;
    if (m < 7) {
      const float nr = cwr * w1r - cwi * w1i;
      const float ni = cwr * w1i + cwi * w1r;
      cwr = nr; cwi = ni;
    }
  }
}

// Out-of-place interior Stockham radix-8 stage. No internal barrier.
template <int SIGN, int S>
__device__ __forceinline__ void stage_r8(const float* X, float* Y,
                                         const int rd[8]) {
  const int t = (int)threadIdx.x;
  const int q = t & (S - 1);
  const int p = t / S;
  float ar[8], ai[8];
#pragma unroll
  for (int j = 0; j < 8; ++j) {
    ar[j] = X[rd[j]];
    ai[j] = X[rd[j] + 64];
  }
  float br[8], bi[8];
  bf8<SIGN>(ar, ai, br, bi);
  tw_write<SIGN, S>(Y, q + 8 * S * p, br, bi, (float)(S * p) * INV_4096);
}

// Conv stage 1 (S=1): loads two real rows as z = x0 + i*x1, fused fwd bf8.
__device__ __forceinline__ void stage1_conv(const float* __restrict__ x0,
                                            const float* __restrict__ x1,
                                            float* Y) {
  const int t = (int)threadIdx.x;
  float ar[8], ai[8];
#pragma unroll
  for (int j = 0; j < 8; ++j) {
    ar[j] = x0[t + 512 * j];
    ai[j] = x1[t + 512 * j];
  }
  float br[8], bi[8];
  bf8<-1>(ar, ai, br, bi);
  tw_write<-1, 1>(Y, 8 * t, br, bi, (float)t * INV_4096);
}

// FUSED MID-STAGE: fwd final (S=512, p=0, twiddle-free) -> Kfull multiply
// -> inverse S=1 butterfly -> twiddled scatter. The spectrum points
// k = t+512m never leave registers (fwd-final output set == inv-S=1 input
// set for the same thread). Kfull[k] = k<=2048 ? kf[k] : conj(kf[4096-k]).
__device__ __forceinline__ void stage_mid_fused(const float* X, float* Y,
                                                const float2* __restrict__ kfrow,
                                                const int rd[8]) {
  const int t = (int)threadIdx.x;
  float ar[8], ai[8];
#pragma unroll
  for (int j = 0; j < 8; ++j) {
    ar[j] = X[rd[j]];
    ai[j] = X[rd[j] + 64];
  }
  float br[8], bi[8];
  bf8<-1>(ar, ai, br, bi);        // fwd final butterfly (twiddle-free)
#pragma unroll
  for (int m = 0; m < 8; ++m) {   // pointwise * Kfull, back into ar/ai
    const int k = t + 512 * m;
    float2 kv;
    if (m <= 3) {
      kv = kfrow[k];              // k <= 2047
    } else {
      kv = kfrow[4096 - k];       // t==0,m==4 -> 2048 (Nyquist)
      kv.y = -kv.y;
    }
    ar[m] = br[m] * kv.x - bi[m] * kv.y;
    ai[m] = br[m] * kv.y + bi[m] * kv.x;
  }
  bf8<1>(ar, ai, br, bi);         // inverse S=1 butterfly
  tw_write<1, 1>(Y, 8 * t, br, bi, (float)t * INV_4096);
}

// Inverse final stage (S=512, twiddle-free), store re->row0, im->row1.
__device__ __forceinline__ void stage4_store(const float* X,
                                             float* __restrict__ y0,
                                             float* __restrict__ y1,
                                             const int rd[8]) {
  const int t = (int)threadIdx.x;
  float ar[8], ai[8];
#pragma unroll
  for (int j = 0; j < 8; ++j) {
    ar[j] = X[rd[j]];
    ai[j] = X[rd[j] + 64];
  }
  float br[8], bi[8];
  bf8<1>(ar, ai, br, bi);
#pragma unroll
  for (int m = 0; m < 8; ++m) {
    const int k = t + 512 * m;
    y0[k] = br[m];
    y1[k] = bi[m];
  }
}

// kfft stage 1: real input (imag = 0), fused fwd bf8.
__device__ __forceinline__ void stage1_k(const float* __restrict__ kin,
                                         float* Y) {
  const int t = (int)threadIdx.x;
  float ar[8], ai[8];
#pragma unroll
  for (int j = 0; j < 8; ++j) {
    ar[j] = kin[t + 512 * j];
    ai[j] = 0.0f;
  }
  float br[8], bi[8];
  bf8<-1>(ar, ai, br, bi);
  tw_write<-1, 1>(Y, 8 * t, br, bi, (float)t * INV_4096);
}

// kfft final stage: store half spectrum [0..2048], 1/4096 scale folded.
__device__ __forceinline__ void stage4_kstore(const float* X,
                                              float2* __restrict__ kfrow,
                                              const int rd[8]) {
  const int t = (int)threadIdx.x;
  float ar[8], ai[8];
#pragma unroll
  for (int j = 0; j < 8; ++j) {
    ar[j] = X[rd[j]];
    ai[j] = X[rd[j] + 64];
  }
  float br[8], bi[8];
  bf8<-1>(ar, ai, br, bi);
  const float sc = 1.0f / 4096.0f;
#pragma unroll
  for (int m = 0; m < 4; ++m) {
    const int k = t + 512 * m;  // 0..2047
    kfrow[k] = make_float2(br[m] * sc, bi[m] * sc);
  }
  if (t == 0) kfrow[2048] = make_float2(br[4] * sc, bi[4] * sc);
}

__global__ __launch_bounds__(NT) void kfft_kernel(const float* __restrict__ kin,
                                                  float2* __restrict__ kf) {
  __shared__ float A_[8192];
  __shared__ float B_[8192];
  const int t = (int)threadIdx.x;
  const int h = (int)blockIdx.x;
  int rd[8];
#pragma unroll
  for (int j = 0; j < 8; ++j) rd[j] = WP(t + 512 * j);
  stage1_k(kin + (size_t)h * 4096, A_);
  __syncthreads();
  stage_r8<-1, 8>(A_, B_, rd);
  __syncthreads();
  stage_r8<-1, 64>(B_, A_, rd);
  __syncthreads();
  stage4_kstore(A_, kf + (size_t)h * KF_LD, rd);
}

__global__ __launch_bounds__(NT) void conv_kernel(const float* __restrict__ x,
                                                  const float2* __restrict__ kf,
                                                  float* __restrict__ y, int H) {
  __shared__ float A_[8192];
  __shared__ float B_[8192];
  const int bi = (int)blockIdx.x;
  const int h = bi % H;
  const int j = bi / H;                 // pair index 0..3 (B=8 -> 4 pairs)
  const size_t r0 = (size_t)(2 * j) * H + h;
  const size_t r1 = r0 + H;
  const float* src0 = x + r0 * 4096;
  const float* src1 = x + r1 * 4096;
  float* dst0 = y + r0 * 4096;
  float* dst1 = y + r1 * 4096;
  const float2* kfrow = kf + (size_t)h * KF_LD;
  const int t = (int)threadIdx.x;
  int rd[8];
#pragma unroll
  for (int jj = 0; jj < 8; ++jj) rd[jj] = WP(t + 512 * jj);
  stage1_conv(src0, src1, A_);       // fwd S=1, fused global load (2 rows)
  __syncthreads();
  stage_r8<-1, 8>(A_, B_, rd);       // fwd S=8
  __syncthreads();
  stage_r8<-1, 64>(B_, A_, rd);      // fwd S=64
  __syncthreads();
  stage_mid_fused(A_, B_, kfrow, rd);// fwd S=512 * Kfull * inv S=1 (in regs)
  __syncthreads();
  stage_r8<1, 8>(B_, A_, rd);        // inv S=8
  __syncthreads();
  stage_r8<1, 64>(A_, B_, rd);       // inv S=64
  __syncthreads();
  stage4_store(B_, dst0, dst1, rd);  // inv S=512, store re/im -> rows
}

extern "C" void kernel_launch(void* const* d_in, const int* in_sizes, int n_in,
                              void* d_out, int out_size, void* d_ws, size_t ws_size,
                              hipStream_t stream) {
  const float* x = (const float*)d_in[0];
  const float* kin = (const float*)d_in[1];
  float* y = (float*)d_out;
  const int H = in_sizes[1] / 4096;    // 768
  const int BH = in_sizes[0] / 4096;   // 6144 rows -> 3072 pairs
  float2* kf = (float2*)d_ws;          // 768*2049*8B = 12.59 MB
  hipLaunchKernelGGL(kfft_kernel, dim3(H), dim3(NT), 0, stream, kin, kf);
  hipLaunchKernelGGL(conv_kernel, dim3(BH / 2), dim3(NT), 0, stream, x, kf, y, H);
}

// Round 16
// 58.401 us; speedup vs baseline: 1.3067x; 1.0374x over previous
//
#include <hip/hip_runtime.h>
#include <math.h>

// FFT circular conv: y[b,h,:] = irfft(rfft(x[b,h,:]) * rfft(k[h,:])), N=4096.
// TWO-ROW SCHEME (z = x[r0] + i*x[r1]; k real => one pointwise serves both)
// + MID-FUSION (fwd-final * Kfull * inv-S=1 all in registers; 6 LDS trips)
// + PERSISTENT LOOP: each block processes NPB=6 pairs with NO extra live
// registers (round 14's failure was +32 prefetch VGPRs, not the loop).
// Loop-back is barrier-free: stage4_store reads B_, next stage1 writes A_,
// and the post-stage1 barrier orders store's B-reads vs S8's B-writes.
// 4096 = 8^4 radix-8 Stockham, ping-pong LDS, re/im [64|64] grouped words
// (ds_read2/write2), SW v2 swizzle, serial sincos chains, v_sin/v_cos revs.

#define NT 512
#define NPB 6
#define KF_LD 2049
#define C_SQRT1_2 0.70710678118654752f
#define INV_4096 2.44140625e-4f

// Word swizzle (bijective involution, keyed on bits>=5).
#define SW(a) ((a) ^ (((a) >> 5) & 31) ^ (((a) >> 2) & 24))
// Point index -> LDS word index of re part (im at +64).
__device__ __forceinline__ int WP(int a) {
  const int s = SW(a);
  return 2 * s - (s & 63);
}

// sn = sin(2*pi*f), cs = cos(2*pi*f); f pre-reduced to [0,1).
__device__ __forceinline__ void sincos_rev(float f, float& sn, float& cs) {
  float s_, c_;
  asm("v_sin_f32 %0, %1" : "=v"(s_) : "v"(f));
  asm("v_cos_f32 %0, %1" : "=v"(c_) : "v"(f));
  sn = s_; cs = c_;
}

template <int SIGN>
__device__ __forceinline__ void bf8(const float ar[8], const float ai[8],
                                    float br[8], float bi[8]) {
  float s0r = ar[0] + ar[4], s0i = ai[0] + ai[4];
  float s1r = ar[0] - ar[4], s1i = ai[0] - ai[4];
  float s2r = ar[2] + ar[6], s2i = ai[2] + ai[6];
  float s3r = ar[2] - ar[6], s3i = ai[2] - ai[6];
  float E0r = s0r + s2r, E0i = s0i + s2i;
  float E2r = s0r - s2r, E2i = s0i - s2i;
  float E1r, E1i, E3r, E3i;
  if (SIGN < 0) { E1r = s1r + s3i; E1i = s1i - s3r; E3r = s1r - s3i; E3i = s1i + s3r; }
  else          { E1r = s1r - s3i; E1i = s1i + s3r; E3r = s1r + s3i; E3i = s1i - s3r; }
  float u0r = ar[1] + ar[5], u0i = ai[1] + ai[5];
  float u1r = ar[1] - ar[5], u1i = ai[1] - ai[5];
  float u2r = ar[3] + ar[7], u2i = ai[3] + ai[7];
  float u3r = ar[3] - ar[7], u3i = ai[3] - ai[7];
  float O0r = u0r + u2r, O0i = u0i + u2i;
  float O2r = u0r - u2r, O2i = u0i - u2i;
  float O1r, O1i, O3r, O3i;
  if (SIGN < 0) { O1r = u1r + u3i; O1i = u1i - u3r; O3r = u1r - u3i; O3i = u1i + u3r; }
  else          { O1r = u1r - u3i; O1i = u1i + u3r; O3r = u1r + u3i; O3i = u1i - u3r; }
  float t1r, t1i, t2r, t2i, t3r, t3i;
  if (SIGN < 0) {
    t1r = C_SQRT1_2 * (O1r + O1i); t1i = C_SQRT1_2 * (O1i - O1r);
    t2r = O2i;  t2i = -O2r;
    t3r = C_SQRT1_2 * (O3i - O3r); t3i = -C_SQRT1_2 * (O3r + O3i);
  } else {
    t1r = C_SQRT1_2 * (O1r - O1i); t1i = C_SQRT1_2 * (O1i + O1r);
    t2r = -O2i; t2i = O2r;
    t3r = -C_SQRT1_2 * (O3r + O3i); t3i = C_SQRT1_2 * (O3r - O3i);
  }
  br[0] = E0r + O0r; bi[0] = E0i + O0i;
  br[4] = E0r - O0r; bi[4] = E0i - O0i;
  br[1] = E1r + t1r; bi[1] = E1i + t1i;
  br[5] = E1r - t1r; bi[5] = E1i - t1i;
  br[2] = E2r + t2r; bi[2] = E2i + t2i;
  br[6] = E2r - t2r; bi[6] = E2i - t2i;
  br[3] = E3r + t3r; bi[3] = E3i + t3i;
  br[7] = E3r - t3r; bi[7] = E3i - t3i;
}

// Twiddled scatter-write: Y[ob+S*m] = b[m] * w^m, w = e^{SIGN*2*pi*i*f1}.
template <int SIGN, int S>
__device__ __forceinline__ void tw_write(float* Y, int ob,
                                         const float br[8], const float bi[8],
                                         float f1) {
  { const int i0 = WP(ob); Y[i0] = br[0]; Y[i0 + 64] = bi[0]; }
  float sn, cs;
  sincos_rev(f1, sn, cs);
  const float w1r = cs, w1i = (SIGN > 0) ? sn : -sn;
  float cwr = w1r, cwi = w1i;
#pragma unroll
  for (int m = 1; m < 8; ++m) {
    const int idx = WP(ob + S * m);
    Y[idx] = br[m] * cwr - bi[m] * cwi;
    Y[idx + 64] = br[m] * cwi + bi[m] * cwr;
    if (m < 7) {
      const float nr = cwr * w1r - cwi * w1i;
      const float ni = cwr * w1i + cwi * w1r;
      cwr = nr; cwi = ni;
    }
  }
}

// Out-of-place interior Stockham radix-8 stage. No internal barrier.
template <int SIGN, int S>
__device__ __forceinline__ void stage_r8(const float* X, float* Y,
                                         const int rd[8]) {
  const int t = (int)threadIdx.x;
  const int q = t & (S - 1);
  const int p = t / S;
  float ar[8], ai[8];
#pragma unroll
  for (int j = 0; j < 8; ++j) {
    ar[j] = X[rd[j]];
    ai[j] = X[rd[j] + 64];
  }
  float br[8], bi[8];
  bf8<SIGN>(ar, ai, br, bi);
  tw_write<SIGN, S>(Y, q + 8 * S * p, br, bi, (float)(S * p) * INV_4096);
}

// Conv stage 1 (S=1): loads two real rows as z = x0 + i*x1, fused fwd bf8.
__device__ __forceinline__ void stage1_conv(const float* __restrict__ x0,
                                            const float* __restrict__ x1,
                                            float* Y) {
  const int t = (int)threadIdx.x;
  float ar[8], ai[8];
#pragma unroll
  for (int j = 0; j < 8; ++j) {
    ar[j] = x0[t + 512 * j];
    ai[j] = x1[t + 512 * j];
  }
  float br[8], bi[8];
  bf8<-1>(ar, ai, br, bi);
  tw_write<-1, 1>(Y, 8 * t, br, bi, (float)t * INV_4096);
}

// FUSED MID-STAGE: fwd final (S=512, p=0, twiddle-free) -> Kfull multiply
// -> inverse S=1 butterfly -> twiddled scatter. Spectrum points k = t+512m
// never leave registers. Kfull[k] = k<=2048 ? kf[k] : conj(kf[4096-k]).
__device__ __forceinline__ void stage_mid_fused(const float* X, float* Y,
                                                const float2* __restrict__ kfrow,
                                                const int rd[8]) {
  const int t = (int)threadIdx.x;
  float ar[8], ai[8];
#pragma unroll
  for (int j = 0; j < 8; ++j) {
    ar[j] = X[rd[j]];
    ai[j] = X[rd[j] + 64];
  }
  float br[8], bi[8];
  bf8<-1>(ar, ai, br, bi);        // fwd final butterfly (twiddle-free)
#pragma unroll
  for (int m = 0; m < 8; ++m) {   // pointwise * Kfull, back into ar/ai
    const int k = t + 512 * m;
    float2 kv;
    if (m <= 3) {
      kv = kfrow[k];              // k <= 2047
    } else {
      kv = kfrow[4096 - k];       // t==0,m==4 -> 2048 (Nyquist)
      kv.y = -kv.y;
    }
    ar[m] = br[m] * kv.x - bi[m] * kv.y;
    ai[m] = br[m] * kv.y + bi[m] * kv.x;
  }
  bf8<1>(ar, ai, br, bi);         // inverse S=1 butterfly
  tw_write<1, 1>(Y, 8 * t, br, bi, (float)t * INV_4096);
}

// Inverse final stage (S=512, twiddle-free), store re->row0, im->row1.
__device__ __forceinline__ void stage4_store(const float* X,
                                             float* __restrict__ y0,
                                             float* __restrict__ y1,
                                             const int rd[8]) {
  const int t = (int)threadIdx.x;
  float ar[8], ai[8];
#pragma unroll
  for (int j = 0; j < 8; ++j) {
    ar[j] = X[rd[j]];
    ai[j] = X[rd[j] + 64];
  }
  float br[8], bi[8];
  bf8<1>(ar, ai, br, bi);
#pragma unroll
  for (int m = 0; m < 8; ++m) {
    const int k = t + 512 * m;
    y0[k] = br[m];
    y1[k] = bi[m];
  }
}

// kfft stage 1: real input (imag = 0), fused fwd bf8.
__device__ __forceinline__ void stage1_k(const float* __restrict__ kin,
                                         float* Y) {
  const int t = (int)threadIdx.x;
  float ar[8], ai[8];
#pragma unroll
  for (int j = 0; j < 8; ++j) {
    ar[j] = kin[t + 512 * j];
    ai[j] = 0.0f;
  }
  float br[8], bi[8];
  bf8<-1>(ar, ai, br, bi);
  tw_write<-1, 1>(Y, 8 * t, br, bi, (float)t * INV_4096);
}

// kfft final stage: store half spectrum [0..2048], 1/4096 scale folded.
__device__ __forceinline__ void stage4_kstore(const float* X,
                                              float2* __restrict__ kfrow,
                                              const int rd[8]) {
  const int t = (int)threadIdx.x;
  float ar[8], ai[8];
#pragma unroll
  for (int j = 0; j < 8; ++j) {
    ar[j] = X[rd[j]];
    ai[j] = X[rd[j] + 64];
  }
  float br[8], bi[8];
  bf8<-1>(ar, ai, br, bi);
  const float sc = 1.0f / 4096.0f;
#pragma unroll
  for (int m = 0; m < 4; ++m) {
    const int k = t + 512 * m;  // 0..2047
    kfrow[k] = make_float2(br[m] * sc, bi[m] * sc);
  }
  if (t == 0) kfrow[2048] = make_float2(br[4] * sc, bi[4] * sc);
}

__global__ __launch_bounds__(NT) void kfft_kernel(const float* __restrict__ kin,
                                                  float2* __restrict__ kf) {
  __shared__ float A_[8192];
  __shared__ float B_[8192];
  const int t = (int)threadIdx.x;
  const int h = (int)blockIdx.x;
  int rd[8];
#pragma unroll
  for (int j = 0; j < 8; ++j) rd[j] = WP(t + 512 * j);
  stage1_k(kin + (size_t)h * 4096, A_);
  __syncthreads();
  stage_r8<-1, 8>(A_, B_, rd);
  __syncthreads();
  stage_r8<-1, 64>(B_, A_, rd);
  __syncthreads();
  stage4_kstore(A_, kf + (size_t)h * KF_LD, rd);
}

__global__ __launch_bounds__(NT) void conv_kernel(const float* __restrict__ x,
                                                  const float2* __restrict__ kf,
                                                  float* __restrict__ y, int H,
                                                  int pairs) {
  __shared__ float A_[8192];
  __shared__ float B_[8192];
  const int t = (int)threadIdx.x;
  int rd[8];
#pragma unroll
  for (int jj = 0; jj < 8; ++jj) rd[jj] = WP(t + 512 * jj);
  const int p0 = (int)blockIdx.x * NPB;
#pragma unroll 1
  for (int ii = 0; ii < NPB; ++ii) {
    const int p = p0 + ii;
    if (p >= pairs) break;
    const int h = p % H;
    const int b2 = p / H;                     // batch-pair index
    const size_t r0 = ((size_t)(2 * b2) * H + (size_t)h) * 4096;
    const float* src0 = x + r0;
    const float* src1 = src0 + (size_t)H * 4096;
    float* dst0 = y + r0;
    float* dst1 = dst0 + (size_t)H * 4096;
    const float2* kfrow = kf + (size_t)h * KF_LD;
    // Loop-back safety: stage1 writes A_ (stage4_store read B_), and the
    // barrier after stage1 orders store's B-reads before S8's B-writes.
    stage1_conv(src0, src1, A_);        // fwd S=1, fused global load (2 rows)
    __syncthreads();
    stage_r8<-1, 8>(A_, B_, rd);        // fwd S=8
    __syncthreads();
    stage_r8<-1, 64>(B_, A_, rd);       // fwd S=64
    __syncthreads();
    stage_mid_fused(A_, B_, kfrow, rd); // fwd S=512 * Kfull * inv S=1 (regs)
    __syncthreads();
    stage_r8<1, 8>(B_, A_, rd);         // inv S=8
    __syncthreads();
    stage_r8<1, 64>(A_, B_, rd);        // inv S=64
    __syncthreads();
    stage4_store(B_, dst0, dst1, rd);   // inv S=512, store re/im -> rows
  }
}

extern "C" void kernel_launch(void* const* d_in, const int* in_sizes, int n_in,
                              void* d_out, int out_size, void* d_ws, size_t ws_size,
                              hipStream_t stream) {
  const float* x = (const float*)d_in[0];
  const float* kin = (const float*)d_in[1];
  float* y = (float*)d_out;
  const int H = in_sizes[1] / 4096;     // 768
  const int BH = in_sizes[0] / 4096;    // 6144 rows -> 3072 pairs
  const int pairs = BH / 2;
  const int blocks = (pairs + NPB - 1) / NPB;  // 512
  float2* kf = (float2*)d_ws;           // 768*2049*8B = 12.59 MB
  hipLaunchKernelGGL(kfft_kernel, dim3(H), dim3(NT), 0, stream, kin, kf);
  hipLaunchKernelGGL(conv_kernel, dim3(blocks), dim3(NT), 0, stream, x, kf, y,
                     H, pairs);
}